// Round 2
// baseline (78.868 us; speedup 1.0000x reference)
//
#include <hip/hip_runtime.h>

// 8-qubit batched statevector sim, v9: 32-lanes-per-element occupancy rewrite.
//   2 elements per wave (e = lane>>5), 8 float2 amps per lane (reg bits r2..r0),
//   5 lane bits s4..s0. Target: ~60 VGPR -> 8 waves/SIMD (was 4 at 128 VGPR),
//   2x latency hiding, half the per-wave straight-line code (I-cache fit).
// Layouts (amp bit b(7-q) holds qubit q):
//   L1: r2..r0 = q0,q1,q2 ; s4..s0 = q3,q4,q5,q6,q7   (init, CRZ, CRX groups 0-2)
//   T1 swaps (r2,s4)(r1,s3)(r0,s2) ->
//   L2: r2..r0 = q3,q4,q5 ; s4..s0 = q0,q1,q2,q6,q7   (CRX groups 3-5)
//   T2 swaps (r1,s1)(r0,s0) ->
//   L3: r2..r0 = q3,q6,q7 ; s4..s0 = q0,q1,q2,q4,q5   (CRX groups 6-7, epilogue)
// Cross-lane: xor1/2/4/8 via DPP (row-local), xor16 via ds_swizzle 0x401F
// (BitMode xor within 32-lane group -> never crosses the element boundary).

static __device__ __forceinline__ float rlane(float v, int src) {
    return __int_as_float(__builtin_amdgcn_readlane(__float_as_int(v), src));
}
template <int CTRL>
static __device__ __forceinline__ float dppf(float x) {
    return __int_as_float(__builtin_amdgcn_update_dpp(0, __float_as_int(x), CTRL, 0xF, 0xF, true));
}
static __device__ __forceinline__ float xor1f(float x) { return dppf<0xB1>(x); }
static __device__ __forceinline__ float xor2f(float x) { return dppf<0x4E>(x); }
static __device__ __forceinline__ float xor4f(float x) { return dppf<0x1B>(dppf<0x141>(x)); }
static __device__ __forceinline__ float xor8f(float x) { return dppf<0x128>(x); }
static __device__ __forceinline__ float swz16f(float x) {
    return __int_as_float(__builtin_amdgcn_ds_swizzle(__float_as_int(x), 0x401F));
}
template <int MS>
static __device__ __forceinline__ float xorT(float x) {
    if constexpr (MS == 1) return xor1f(x);
    else if constexpr (MS == 2) return xor2f(x);
    else if constexpr (MS == 4) return xor4f(x);
    else if constexpr (MS == 8) return xor8f(x);
    else return swz16f(x);
}
template <int MS>
static __device__ __forceinline__ float2 xorT2(float2 v) {
    float2 t; t.x = xorT<MS>(v.x); t.y = xorT<MS>(v.y); return t;
}
static __device__ __forceinline__ float2 cmul(float2 a, float2 b) {
    float2 t;
    t.x = a.x * b.x - a.y * b.y;
    t.y = a.x * b.y + a.y * b.x;
    return t;
}
// CRX half-rotation: c*t - i*s*u  ->  (c*t.x + s*u.y, c*t.y - s*u.x)
static __device__ __forceinline__ float2 rotA(float2 t, float2 u, float c, float s) {
    float2 d;
    d.x = c * t.x + s * u.y;
    d.y = c * t.y - s * u.x;
    return d;
}
// Lane-target CRX on a[r]: partner at lane s^MS.
template <int MS>
static __device__ __forceinline__ void crxLane1(float2& ar, float c, float sv) {
    const float px = xorT<MS>(ar.x);
    const float py = xorT<MS>(ar.y);
    const float mx = py * sv;
    const float my = px * sv;
    ar.x = __builtin_fmaf(c, ar.x, mx);
    ar.y = __builtin_fmaf(c, ar.y, -my);
}
// Gate with ctrl = reg bit RC, target = reg bit log2(MT): 2 active pairs.
template <int RC, int MT>
static __device__ __forceinline__ void crxReg(float2 (&a)[8], float c, float s) {
#pragma unroll
    for (int r = 0; r < 8; ++r) {
        if (!((r >> RC) & 1)) continue;
        if (r & MT) continue;
        const int rp = r | MT;
        const float2 t = a[r], u = a[rp];
        a[r]  = rotA(t, u, c, s);
        a[rp] = rotA(u, t, c, s);
    }
}
// Gate with ctrl = reg bit RC, target = lane bit log2(MS): 4 active regs.
template <int RC, int MS>
static __device__ __forceinline__ void crxLaneG(float2 (&a)[8], float c, float sv) {
#pragma unroll
    for (int r = 0; r < 8; ++r) {
        if (!((r >> RC) & 1)) continue;
        crxLane1<MS>(a[r], c, sv);
    }
}
// xor-swap stage exchanging reg bit log2(MT) with lane bit log2(MS).
template <int MT, int MS>
static __device__ __forceinline__ void transposeStage(float2 (&a)[8], int s) {
    const bool sk = (s & MS) != 0;
#pragma unroll
    for (int r = 0; r < 8; ++r) {
        if (r & MT) continue;
        const int rp = r | MT;
        const float2 tp = xorT2<MS>(a[rp]);
        const float2 tr = xorT2<MS>(a[r]);
        a[r].x  = sk ? tp.x : a[r].x;
        a[r].y  = sk ? tp.y : a[r].y;
        a[rp].x = sk ? a[rp].x : tr.x;
        a[rp].y = sk ? a[rp].y : tr.y;
    }
}

#define G(gi) rlane(gcv, gi), rlane(gsv, gi)

__global__ __launch_bounds__(256, 8) void qsim_kernel(const float* __restrict__ X,
                                                      const float* __restrict__ W,
                                                      float* __restrict__ out,
                                                      int B) {
    const int lane = threadIdx.x & 63;
    const int wv = threadIdx.x >> 6;    // wave in block: 0..3
    const int e = lane >> 5;            // element slot in wave: 0..1
    const int s = lane & 31;            // sublane within element
    const int b = (blockIdx.x * 4 + wv) * 2 + e;
    const bool active = (b < B);
    const int bc = active ? b : (B - 1);   // clamp loads; keep all lanes alive for DPP/swizzle

    // ---- CRX trig: lane gi (<56) holds cos/sin of 0.5*W[1+i, j] (wave-shared) ----
    float gcv = 1.0f, gsv = 0.0f;
    if (lane < 56) {
        const int i = lane / 7;
        const int jj = lane - 7 * i;
        const int j = jj + (jj >= i ? 1 : 0);
        const float h = 0.5f * W[(1 + i) * 72 + j];
        __sincosf(h, &gsv, &gcv);
    }

    // ---- per-qubit fused H->RZ->RY first column (sublane q computes qubit q) ----
    float u0r, u0i, u1r, u1i;
    {
        const int q = s & 7;
        float2 xq = ((const float2*)X)[bc * 8 + q];
        float cz, sz, cy, sy;
        __sincosf(0.5f * xq.x, &sz, &cz);
        __sincosf(0.5f * xq.y, &sy, &cy);
        u0r = (cy - sy) * cz;  u0i = -(cy + sy) * sz;
        u1r = (cy + sy) * cz;  u1i = (cy - sy) * sz;
    }

    // ---- product state in L1 ----
    // lane part: qubits 3..7 -> s bits 4..0  (bit = (s >> (7-q)) & 1)
    float2 P; P.x = 1.0f; P.y = 0.0f;
#pragma unroll
    for (int q = 3; q < 8; ++q) {
        const int src = (e << 5) + q;
        const float a0r = __shfl(u0r, src, 64), a0i = __shfl(u0i, src, 64);
        const float a1r = __shfl(u1r, src, 64), a1i = __shfl(u1i, src, 64);
        const int bit = (s >> (7 - q)) & 1;
        float2 v; v.x = bit ? a1r : a0r; v.y = bit ? a1i : a0i;
        P = cmul(P, v);
    }
    // reg part: qubits 0..2 -> r bits 2..0
    float2 w0[3], w1[3];
#pragma unroll
    for (int k = 0; k < 3; ++k) {
        const int src = (e << 5) + k;
        w0[k].x = __shfl(u0r, src, 64);  w0[k].y = __shfl(u0i, src, 64);
        w1[k].x = __shfl(u1r, src, 64);  w1[k].y = __shfl(u1i, src, 64);
    }
    float2 a[8];
    {
        float2 t1[2];
        t1[0] = w0[0];
        t1[1] = w1[0];
        float2 t2[4];
#pragma unroll
        for (int h = 0; h < 2; ++h) {
            t2[h * 2 + 0] = cmul(t1[h], w0[1]);
            t2[h * 2 + 1] = cmul(t1[h], w1[1]);
        }
#pragma unroll
        for (int h = 0; h < 4; ++h) {
            a[h * 2 + 0] = cmul(P, cmul(t2[h], w0[2]));
            a[h * 2 + 1] = cmul(P, cmul(t2[h], w1[2]));
        }
    }

    // ---- CRZ ring fused into one diagonal phase per amp (L1 bit mapping) ----
    // amp-bit pairs (ctrl,target,w): (7,6,w0)(6,5,w1)(5,4,w2)(4,3,w3)(3,2,w4)(2,1,w5)(1,0,w6)(0,7,w7)
    // L1: b7..b5 = r2..r0 ; b4..b0 = s4..s0.
    {
        const float wv0 = W[0], wv1 = W[1], wv2 = W[2], wv3 = W[3];
        const float wv4 = W[4], wv5 = W[5], wv6 = W[6], wv7 = W[7];
        const int s4b = (s >> 4) & 1, s3b = (s >> 3) & 1, s2b = (s >> 2) & 1,
                  s1b = (s >> 1) & 1, s0b = s & 1;
        float phiS = 0.0f;
        phiS += s4b ? (s3b ? wv3 : -wv3) : 0.0f;   // pair (4,3)
        phiS += s3b ? (s2b ? wv4 : -wv4) : 0.0f;   // pair (3,2)
        phiS += s2b ? (s1b ? wv5 : -wv5) : 0.0f;   // pair (2,1)
        phiS += s1b ? (s0b ? wv6 : -wv6) : 0.0f;   // pair (1,0)
        const float termB = s0b ? wv7 : 0.0f;      // pair (0,7): ctrl s0, sign by r2
        const float termC = s4b ? wv2 : -wv2;      // pair (5,4): ctrl r0, sign by s4
#pragma unroll
        for (int r = 0; r < 8; ++r) {
            const int r2 = (r >> 2) & 1, r1 = (r >> 1) & 1, r0 = r & 1;
            float phi = phiS + (r2 ? termB : -termB);
            if (r2) phi += r1 ? wv0 : -wv0;        // pair (7,6)
            if (r1) phi += r0 ? wv1 : -wv1;        // pair (6,5)
            if (r0) phi += termC;
            float2 ph;
            __sincosf(0.5f * phi, &ph.y, &ph.x);
            a[r] = cmul(a[r], ph);
        }
    }

    // ---- CRX phase A (L1): groups 0-2, ctrl = reg bit (2-i) ----
    // group 0 (rc=2): tgt q1->mt2, q2->mt1, q3->ms16, q4->ms8, q5->ms4, q6->ms2, q7->ms1
    crxReg<2, 2>(a, G(0));
    crxReg<2, 1>(a, G(1));
    crxLaneG<2, 16>(a, G(2));
    crxLaneG<2, 8>(a, G(3));
    crxLaneG<2, 4>(a, G(4));
    crxLaneG<2, 2>(a, G(5));
    crxLaneG<2, 1>(a, G(6));
    // group 1 (rc=1)
    crxReg<1, 4>(a, G(7));
    crxReg<1, 1>(a, G(8));
    crxLaneG<1, 16>(a, G(9));
    crxLaneG<1, 8>(a, G(10));
    crxLaneG<1, 4>(a, G(11));
    crxLaneG<1, 2>(a, G(12));
    crxLaneG<1, 1>(a, G(13));
    // group 2 (rc=0)
    crxReg<0, 4>(a, G(14));
    crxReg<0, 2>(a, G(15));
    crxLaneG<0, 16>(a, G(16));
    crxLaneG<0, 8>(a, G(17));
    crxLaneG<0, 4>(a, G(18));
    crxLaneG<0, 2>(a, G(19));
    crxLaneG<0, 1>(a, G(20));

    // ---- T1: L1 -> L2, swap (r2,s4)(r1,s3)(r0,s2) ----
    transposeStage<4, 16>(a, s);
    transposeStage<2, 8>(a, s);
    transposeStage<1, 4>(a, s);

    // ---- CRX phase B (L2): groups 3-5, ctrl = reg bit (5-i) ----
    // L2: r2..r0 = q3,q4,q5 ; s4..s0 = q0,q1,q2,q6,q7
    // group 3 (rc=2): q0->ms16, q1->ms8, q2->ms4, q4->mt2, q5->mt1, q6->ms2, q7->ms1
    crxLaneG<2, 16>(a, G(21));
    crxLaneG<2, 8>(a, G(22));
    crxLaneG<2, 4>(a, G(23));
    crxReg<2, 2>(a, G(24));
    crxReg<2, 1>(a, G(25));
    crxLaneG<2, 2>(a, G(26));
    crxLaneG<2, 1>(a, G(27));
    // group 4 (rc=1)
    crxLaneG<1, 16>(a, G(28));
    crxLaneG<1, 8>(a, G(29));
    crxLaneG<1, 4>(a, G(30));
    crxReg<1, 4>(a, G(31));
    crxReg<1, 1>(a, G(32));
    crxLaneG<1, 2>(a, G(33));
    crxLaneG<1, 1>(a, G(34));
    // group 5 (rc=0)
    crxLaneG<0, 16>(a, G(35));
    crxLaneG<0, 8>(a, G(36));
    crxLaneG<0, 4>(a, G(37));
    crxReg<0, 4>(a, G(38));
    crxReg<0, 2>(a, G(39));
    crxLaneG<0, 2>(a, G(40));
    crxLaneG<0, 1>(a, G(41));

    // ---- T2: L2 -> L3, swap (r1,s1)(r0,s0) ----
    transposeStage<2, 2>(a, s);
    transposeStage<1, 1>(a, s);

    // ---- CRX phase C (L3): groups 6-7 ----
    // L3: r2..r0 = q3,q6,q7 ; s4..s0 = q0,q1,q2,q4,q5
    // group 6 (rc=1): q0->ms16, q1->ms8, q2->ms4, q3->mt4, q4->ms2, q5->ms1, q7->mt1
    crxLaneG<1, 16>(a, G(42));
    crxLaneG<1, 8>(a, G(43));
    crxLaneG<1, 4>(a, G(44));
    crxReg<1, 4>(a, G(45));
    crxLaneG<1, 2>(a, G(46));
    crxLaneG<1, 1>(a, G(47));
    crxReg<1, 1>(a, G(48));
    // group 7 (rc=0): q6->mt2
    crxLaneG<0, 16>(a, G(49));
    crxLaneG<0, 8>(a, G(50));
    crxLaneG<0, 4>(a, G(51));
    crxReg<0, 4>(a, G(52));
    crxLaneG<0, 2>(a, G(53));
    crxLaneG<0, 1>(a, G(54));
    crxReg<0, 2>(a, G(55));

    // ---- probabilities + all 8 <Z_q> in L3 ----
    // reg bits: r2=q3, r1=q6, r0=q7 ; lane bits: s4=q0, s3=q1, s2=q2, s1=q4, s0=q5
    float p[8];
#pragma unroll
    for (int r = 0; r < 8; ++r) p[r] = a[r].x * a[r].x + a[r].y * a[r].y;
    float s4v[4], E7 = 0.0f;
#pragma unroll
    for (int k = 0; k < 4; ++k) { s4v[k] = p[2 * k] + p[2 * k + 1]; E7 += p[2 * k] - p[2 * k + 1]; }
    float s2v[2], E6 = 0.0f;
#pragma unroll
    for (int k = 0; k < 2; ++k) { s2v[k] = s4v[2 * k] + s4v[2 * k + 1]; E6 += s4v[2 * k] - s4v[2 * k + 1]; }
    float A  = s2v[0] + s2v[1];
    float E3 = s2v[0] - s2v[1];
    float Dq5, Dq4, Dq2, Dq1, Dq0;
    { const float t = xor1f(A); Dq5 = A - t; A += t;
      E3 += xor1f(E3); E6 += xor1f(E6); E7 += xor1f(E7); }
    { const float t = xor2f(A); Dq4 = A - t; A += t;
      Dq5 += xor2f(Dq5);
      E3 += xor2f(E3); E6 += xor2f(E6); E7 += xor2f(E7); }
    { const float t = xor4f(A); Dq2 = A - t; A += t;
      Dq5 += xor4f(Dq5); Dq4 += xor4f(Dq4);
      E3 += xor4f(E3); E6 += xor4f(E6); E7 += xor4f(E7); }
    { const float t = xor8f(A); Dq1 = A - t; A += t;
      Dq5 += xor8f(Dq5); Dq4 += xor8f(Dq4); Dq2 += xor8f(Dq2);
      E3 += xor8f(E3); E6 += xor8f(E6); E7 += xor8f(E7); }
    { const float t = swz16f(A); Dq0 = A - t;
      Dq5 += swz16f(Dq5); Dq4 += swz16f(Dq4); Dq2 += swz16f(Dq2); Dq1 += swz16f(Dq1);
      E3 += swz16f(E3); E6 += swz16f(E6); E7 += swz16f(E7); }

    if (s == 0 && active) {
        const float sc = 1.0f / 256.0f;  // (1/sqrt2)^8 squared, folded out of u's
        float4 o0, o1;
        o0.x = Dq0 * sc; o0.y = Dq1 * sc; o0.z = Dq2 * sc; o0.w = E3 * sc;
        o1.x = Dq4 * sc; o1.y = Dq5 * sc; o1.z = E6 * sc;  o1.w = E7 * sc;
        float4* o = (float4*)(out + b * 8);
        o[0] = o0;
        o[1] = o1;
    }
}

extern "C" void kernel_launch(void* const* d_in, const int* in_sizes, int n_in,
                              void* d_out, int out_size, void* d_ws, size_t ws_size,
                              hipStream_t stream) {
    const float* X = (const float*)d_in[0];
    const float* W = (const float*)d_in[1];
    float* out = (float*)d_out;
    const int B = in_sizes[0] / 16;     // 2*N floats per row
    const int blocks = (B + 7) / 8;     // 4 waves x 2 elements per 256-thread block
    qsim_kernel<<<blocks, 256, 0, stream>>>(X, W, out, B);
}